// Round 2
// baseline (11412.069 us; speedup 1.0000x reference)
//
#include <hip/hip_runtime.h>
#include <hip/hip_bf16.h>

#define DM 1024
#define NH 16
#define DK 64
#define BB 4
#define SS 2048
#define EPSV 1e-6f

// C[M,N] = A[M,K] @ W[K,N], all f32. 64x64 tile, K-step 16.
__global__ __launch_bounds__(256) void gemm_k(const float* __restrict__ A,
                                              const float* __restrict__ W,
                                              float* __restrict__ C,
                                              int M, int N, int K) {
  const int TM = 64, TN = 64, TK = 16;
  __shared__ float As[TK][TM + 1];
  __shared__ float Ws[TK][TN + 1];
  int bm = blockIdx.y * TM, bn = blockIdx.x * TN;
  int tid = threadIdx.x;
  int tx = tid & 15, ty = tid >> 4;
  float acc[4][4] = {};
  for (int k0 = 0; k0 < K; k0 += TK) {
    {
      // A tile: 64 rows x 16 k = 256 float4 loads (k-contiguous)
      int m = tid >> 2, kq = (tid & 3) * 4;
      float4 av = *(const float4*)&A[(size_t)(bm + m) * K + k0 + kq];
      As[kq + 0][m] = av.x;
      As[kq + 1][m] = av.y;
      As[kq + 2][m] = av.z;
      As[kq + 3][m] = av.w;
      // W tile: 16 k x 64 n = 256 float4 loads (n-contiguous)
      int kk = tid >> 4, nq = (tid & 15) * 4;
      float4 wv = *(const float4*)&W[(size_t)(k0 + kk) * N + bn + nq];
      Ws[kk][nq + 0] = wv.x;
      Ws[kk][nq + 1] = wv.y;
      Ws[kk][nq + 2] = wv.z;
      Ws[kk][nq + 3] = wv.w;
    }
    __syncthreads();
#pragma unroll
    for (int kk = 0; kk < TK; ++kk) {
      float a[4], w[4];
#pragma unroll
      for (int i = 0; i < 4; ++i) a[i] = As[kk][ty * 4 + i];
#pragma unroll
      for (int j = 0; j < 4; ++j) w[j] = Ws[kk][tx * 4 + j];
#pragma unroll
      for (int i = 0; i < 4; ++i)
#pragma unroll
        for (int j = 0; j < 4; ++j) acc[i][j] += a[i] * w[j];
    }
    __syncthreads();
  }
#pragma unroll
  for (int i = 0; i < 4; ++i)
#pragma unroll
    for (int j = 0; j < 4; ++j)
      C[(size_t)(bm + ty * 4 + i) * N + bn + tx * 4 + j] = acc[i][j];
}

// One block per (b, h, q): scores -> masked -> softmax -> PV.
// Q,K,V layout: [B, S, H, D] f32. O same layout.
__global__ __launch_bounds__(256) void attn_k(const float* __restrict__ Q,
                                              const float* __restrict__ K,
                                              const float* __restrict__ V,
                                              const int* __restrict__ mask,
                                              float* __restrict__ O) {
  int idx = blockIdx.x;
  int q = idx & (SS - 1);
  int h = (idx >> 11) & (NH - 1);
  int b = idx >> 15;
  __shared__ float sc[SS];
  __shared__ float qs[DK];
  __shared__ float red[256];
  __shared__ float part[4][DK];
  int tid = threadIdx.x;
  const float* qp = Q + (((size_t)(b * SS + q)) * NH + h) * DK;
  if (tid < DK) qs[tid] = qp[tid];
  __syncthreads();
  const int* mrow = mask + ((size_t)b * SS + q) * SS;
  float lmax = -1e30f;
  for (int k = tid; k < SS; k += 256) {
    const float4* kp4 = (const float4*)(K + (((size_t)(b * SS + k)) * NH + h) * DK);
    float s = 0.f;
#pragma unroll
    for (int d4 = 0; d4 < DK / 4; ++d4) {
      float4 kv = kp4[d4];
      s += qs[d4 * 4 + 0] * kv.x + qs[d4 * 4 + 1] * kv.y + qs[d4 * 4 + 2] * kv.z +
           qs[d4 * 4 + 3] * kv.w;
    }
    s *= 0.125f;  // 1/sqrt(64)
    if (mrow[k] == 0) s = EPSV;
    sc[k] = s;
    lmax = fmaxf(lmax, s);
  }
  red[tid] = lmax;
  __syncthreads();
  for (int st = 128; st > 0; st >>= 1) {
    if (tid < st) red[tid] = fmaxf(red[tid], red[tid + st]);
    __syncthreads();
  }
  float mx = red[0];
  __syncthreads();
  float lsum = 0.f;
  for (int k = tid; k < SS; k += 256) {
    float p = __expf(sc[k] - mx);
    sc[k] = p;
    lsum += p;
  }
  red[tid] = lsum;
  __syncthreads();
  for (int st = 128; st > 0; st >>= 1) {
    if (tid < st) red[tid] += red[tid + st];
    __syncthreads();
  }
  float inv = 1.f / red[0];
  int d = tid & 63, g = tid >> 6;
  float acc = 0.f;
  for (int k = g * (SS / 4); k < (g + 1) * (SS / 4); ++k)
    acc += sc[k] * V[(((size_t)(b * SS + k)) * NH + h) * DK + d];
  part[g][d] = acc;
  __syncthreads();
  if (g == 0) {
    float r = (part[0][d] + part[1][d] + part[2][d] + part[3][d]) * inv;
    O[(((size_t)(b * SS + q)) * NH + h) * DK + d] = r;
  }
}

// Residual + LayerNorm (ddof=1 std, eps added to std), f32 out.
__global__ __launch_bounds__(256) void ln_k(const float* __restrict__ P,
                                            const float* __restrict__ X,
                                            const float* __restrict__ gamma,
                                            const float* __restrict__ beta,
                                            float* __restrict__ out) {
  int row = blockIdx.x, tid = threadIdx.x;
  __shared__ float buf[DM];
  __shared__ float red[256];
  float local = 0.f;
  for (int i = tid; i < DM; i += 256) {
    float v = P[(size_t)row * DM + i] + X[(size_t)row * DM + i];
    buf[i] = v;
    local += v;
  }
  red[tid] = local;
  __syncthreads();
  for (int st = 128; st > 0; st >>= 1) {
    if (tid < st) red[tid] += red[tid + st];
    __syncthreads();
  }
  float mean = red[0] * (1.f / DM);
  __syncthreads();
  float l2 = 0.f;
  for (int i = tid; i < DM; i += 256) {
    float dd = buf[i] - mean;
    l2 += dd * dd;
  }
  red[tid] = l2;
  __syncthreads();
  for (int st = 128; st > 0; st >>= 1) {
    if (tid < st) red[tid] += red[tid + st];
    __syncthreads();
  }
  float stdv = sqrtf(red[0] / (DM - 1));
  float inv = 1.f / (stdv + EPSV);
  for (int i = tid; i < DM; i += 256) {
    float y = gamma[i] * (buf[i] - mean) * inv + beta[i];
    out[(size_t)row * DM + i] = y;
  }
}

extern "C" void kernel_launch(void* const* d_in, const int* in_sizes, int n_in,
                              void* d_out, int out_size, void* d_ws, size_t ws_size,
                              hipStream_t stream) {
  const float* xq = (const float*)d_in[0];
  const float* xk = (const float*)d_in[1];
  const float* xv = (const float*)d_in[2];
  const int* mask = (const int*)d_in[3];
  const float* wq = (const float*)d_in[4];
  const float* wk = (const float*)d_in[5];
  const float* wv = (const float*)d_in[6];
  const float* w0 = (const float*)d_in[7];
  const float* gamma = (const float*)d_in[8];
  const float* beta = (const float*)d_in[9];
  float* out = (float*)d_out;

  const size_t NE = (size_t)BB * SS * DM;  // 8,388,608 elements per tensor
  float* Q = (float*)d_ws;
  float* K = Q + NE;
  float* V = K + NE;
  float* AO = V + NE;
  float* P = Q;  // projection output reuses Q's buffer (Q dead after attn)

  const int M = BB * SS;  // 8192
  dim3 gg(DM / 64, M / 64);
  gemm_k<<<gg, 256, 0, stream>>>(xq, wq, Q, M, DM, DM);
  gemm_k<<<gg, 256, 0, stream>>>(xk, wk, K, M, DM, DM);
  gemm_k<<<gg, 256, 0, stream>>>(xv, wv, V, M, DM, DM);
  attn_k<<<BB * NH * SS, 256, 0, stream>>>(Q, K, V, mask, AO);
  gemm_k<<<gg, 256, 0, stream>>>(AO, w0, P, M, DM, DM);
  ln_k<<<M, 256, 0, stream>>>(P, xq, gamma, beta, out);
}

// Round 3
// 5333.941 us; speedup vs baseline: 2.1395x; 2.1395x over previous
//
#include <hip/hip_runtime.h>
#include <hip/hip_bf16.h>

#define DM 1024
#define NH 16
#define DK 64
#define BB 4
#define SS 2048
#define EPSV 1e-6f

// C[M,N] = A[M,K] @ W[K,N], all f32. 64x64 tile, K-step 16.
__global__ __launch_bounds__(256) void gemm_k(const float* __restrict__ A,
                                              const float* __restrict__ W,
                                              float* __restrict__ C,
                                              int M, int N, int K) {
  const int TK = 16;
  __shared__ float As[TK][64 + 1];
  __shared__ float Ws[TK][64 + 1];
  int bm = blockIdx.y * 64, bn = blockIdx.x * 64;
  int tid = threadIdx.x;
  int tx = tid & 15, ty = tid >> 4;
  float acc[4][4] = {};
  for (int k0 = 0; k0 < K; k0 += TK) {
    {
      int m = tid >> 2, kq = (tid & 3) * 4;
      float4 av = *(const float4*)&A[(size_t)(bm + m) * K + k0 + kq];
      As[kq + 0][m] = av.x;
      As[kq + 1][m] = av.y;
      As[kq + 2][m] = av.z;
      As[kq + 3][m] = av.w;
      int kk = tid >> 4, nq = (tid & 15) * 4;
      float4 wv = *(const float4*)&W[(size_t)(k0 + kk) * N + bn + nq];
      Ws[kk][nq + 0] = wv.x;
      Ws[kk][nq + 1] = wv.y;
      Ws[kk][nq + 2] = wv.z;
      Ws[kk][nq + 3] = wv.w;
    }
    __syncthreads();
#pragma unroll
    for (int kk = 0; kk < TK; ++kk) {
      float a[4], w[4];
#pragma unroll
      for (int i = 0; i < 4; ++i) a[i] = As[kk][ty * 4 + i];
#pragma unroll
      for (int j = 0; j < 4; ++j) w[j] = Ws[kk][tx * 4 + j];
#pragma unroll
      for (int i = 0; i < 4; ++i)
#pragma unroll
        for (int j = 0; j < 4; ++j) acc[i][j] += a[i] * w[j];
    }
    __syncthreads();
  }
#pragma unroll
  for (int i = 0; i < 4; ++i)
#pragma unroll
    for (int j = 0; j < 4; ++j)
      C[(size_t)(bm + ty * 4 + i) * N + bn + tx * 4 + j] = acc[i][j];
}

// Flash-style tiled attention: one block per (b, h, 64-q tile).
// Q,K,V,O layout: [B, S, H, D] f32. Online softmax; mask==0 -> score=1e-6.
#define PADW 68  // row stride in floats: 16B-aligned, column access 2-way max
__global__ __launch_bounds__(256) void attn_tile_k(const float* __restrict__ Q,
                                                   const float* __restrict__ K,
                                                   const float* __restrict__ V,
                                                   const int* __restrict__ mask,
                                                   float* __restrict__ O) {
  __shared__ float Qs[64][PADW];   // [q][d], pre-scaled by 1/8
  __shared__ float KsT[64][PADW];  // [d][k]  (transposed)
  __shared__ float Vs[64][PADW];   // [k][d]
  __shared__ float Ps[64][PADW];   // [q][k]
  int b = blockIdx.z, h = blockIdx.y, q0 = blockIdx.x * 64;
  int tid = threadIdx.x;
  int tx = tid & 15, ty = tid >> 4;
  int qy = ty * 4, dx = tx * 4;
  int sr = tid >> 4, sc = (tid & 15) * 4;  // staging row/col

#pragma unroll
  for (int rr = 0; rr < 4; ++rr) {
    int r = sr + rr * 16;
    float4 qv = *(const float4*)&Q[(((size_t)b * SS + q0 + r) * NH + h) * DK + sc];
    Qs[r][sc + 0] = qv.x * 0.125f;
    Qs[r][sc + 1] = qv.y * 0.125f;
    Qs[r][sc + 2] = qv.z * 0.125f;
    Qs[r][sc + 3] = qv.w * 0.125f;
  }

  float m[4], l[4], acc[4][4];
#pragma unroll
  for (int i = 0; i < 4; ++i) {
    m[i] = -1e30f;
    l[i] = 0.f;
#pragma unroll
    for (int j = 0; j < 4; ++j) acc[i][j] = 0.f;
  }

  for (int kt = 0; kt < SS / 64; ++kt) {
    int k0 = kt * 64;
#pragma unroll
    for (int rr = 0; rr < 4; ++rr) {
      int r = sr + rr * 16;
      float4 kv = *(const float4*)&K[(((size_t)b * SS + k0 + r) * NH + h) * DK + sc];
      KsT[sc + 0][r] = kv.x;
      KsT[sc + 1][r] = kv.y;
      KsT[sc + 2][r] = kv.z;
      KsT[sc + 3][r] = kv.w;
      float4 vv = *(const float4*)&V[(((size_t)b * SS + k0 + r) * NH + h) * DK + sc];
      *(float4*)&Vs[r][sc] = vv;
    }
    int4 mi[4];
#pragma unroll
    for (int i = 0; i < 4; ++i)
      mi[i] = *(const int4*)&mask[((size_t)b * SS + q0 + qy + i) * SS + k0 + dx];
    __syncthreads();

    float s[4][4] = {};
#pragma unroll
    for (int d = 0; d < 64; d += 4) {
      float av[4][4];
#pragma unroll
      for (int i = 0; i < 4; ++i) {
        float4 t = *(const float4*)&Qs[qy + i][d];
        av[i][0] = t.x; av[i][1] = t.y; av[i][2] = t.z; av[i][3] = t.w;
      }
#pragma unroll
      for (int c = 0; c < 4; ++c) {
        float4 t = *(const float4*)&KsT[d + c][dx];
        float kc[4] = {t.x, t.y, t.z, t.w};
#pragma unroll
        for (int i = 0; i < 4; ++i)
#pragma unroll
          for (int j = 0; j < 4; ++j) s[i][j] += av[i][c] * kc[j];
      }
    }
    // mask (mask==0 -> eps), then online softmax per q-row
    float alpha[4];
#pragma unroll
    for (int i = 0; i < 4; ++i) {
      s[i][0] = mi[i].x ? s[i][0] : EPSV;
      s[i][1] = mi[i].y ? s[i][1] : EPSV;
      s[i][2] = mi[i].z ? s[i][2] : EPSV;
      s[i][3] = mi[i].w ? s[i][3] : EPSV;
      float tm = fmaxf(fmaxf(s[i][0], s[i][1]), fmaxf(s[i][2], s[i][3]));
#pragma unroll
      for (int off = 1; off < 16; off <<= 1) tm = fmaxf(tm, __shfl_xor(tm, off));
      float mnew = fmaxf(m[i], tm);
      alpha[i] = __expf(m[i] - mnew);
      float p0 = __expf(s[i][0] - mnew);
      float p1 = __expf(s[i][1] - mnew);
      float p2 = __expf(s[i][2] - mnew);
      float p3 = __expf(s[i][3] - mnew);
      float rs = (p0 + p1) + (p2 + p3);
#pragma unroll
      for (int off = 1; off < 16; off <<= 1) rs += __shfl_xor(rs, off);
      l[i] = l[i] * alpha[i] + rs;
      m[i] = mnew;
      *(float4*)&Ps[qy + i][dx] = make_float4(p0, p1, p2, p3);
    }
    __syncthreads();

#pragma unroll
    for (int i = 0; i < 4; ++i)
#pragma unroll
      for (int j = 0; j < 4; ++j) acc[i][j] *= alpha[i];
#pragma unroll
    for (int k = 0; k < 64; k += 4) {
      float pv[4][4];
#pragma unroll
      for (int i = 0; i < 4; ++i) {
        float4 t = *(const float4*)&Ps[qy + i][k];
        pv[i][0] = t.x; pv[i][1] = t.y; pv[i][2] = t.z; pv[i][3] = t.w;
      }
#pragma unroll
      for (int c = 0; c < 4; ++c) {
        float4 t = *(const float4*)&Vs[k + c][dx];
        float vv[4] = {t.x, t.y, t.z, t.w};
#pragma unroll
        for (int i = 0; i < 4; ++i)
#pragma unroll
          for (int j = 0; j < 4; ++j) acc[i][j] += pv[i][c] * vv[j];
      }
    }
    __syncthreads();
  }

#pragma unroll
  for (int i = 0; i < 4; ++i) {
    float inv = 1.f / l[i];
    float4 o = make_float4(acc[i][0] * inv, acc[i][1] * inv, acc[i][2] * inv, acc[i][3] * inv);
    *(float4*)&O[(((size_t)b * SS + q0 + qy + i) * NH + h) * DK + dx] = o;
  }
}

// Residual + LayerNorm (ddof=1 std, eps added to std), f32 out.
__global__ __launch_bounds__(256) void ln_k(const float* __restrict__ P,
                                            const float* __restrict__ X,
                                            const float* __restrict__ gamma,
                                            const float* __restrict__ beta,
                                            float* __restrict__ out) {
  int row = blockIdx.x, tid = threadIdx.x;
  __shared__ float buf[DM];
  __shared__ float red[256];
  float local = 0.f;
  for (int i = tid; i < DM; i += 256) {
    float v = P[(size_t)row * DM + i] + X[(size_t)row * DM + i];
    buf[i] = v;
    local += v;
  }
  red[tid] = local;
  __syncthreads();
  for (int st = 128; st > 0; st >>= 1) {
    if (tid < st) red[tid] += red[tid + st];
    __syncthreads();
  }
  float mean = red[0] * (1.f / DM);
  __syncthreads();
  float l2 = 0.f;
  for (int i = tid; i < DM; i += 256) {
    float dd = buf[i] - mean;
    l2 += dd * dd;
  }
  red[tid] = l2;
  __syncthreads();
  for (int st = 128; st > 0; st >>= 1) {
    if (tid < st) red[tid] += red[tid + st];
    __syncthreads();
  }
  float stdv = sqrtf(red[0] / (DM - 1));
  float inv = 1.f / (stdv + EPSV);
  for (int i = tid; i < DM; i += 256) {
    float y = gamma[i] * (buf[i] - mean) * inv + beta[i];
    out[(size_t)row * DM + i] = y;
  }
}

extern "C" void kernel_launch(void* const* d_in, const int* in_sizes, int n_in,
                              void* d_out, int out_size, void* d_ws, size_t ws_size,
                              hipStream_t stream) {
  const float* xq = (const float*)d_in[0];
  const float* xk = (const float*)d_in[1];
  const float* xv = (const float*)d_in[2];
  const int* mask = (const int*)d_in[3];
  const float* wq = (const float*)d_in[4];
  const float* wk = (const float*)d_in[5];
  const float* wv = (const float*)d_in[6];
  const float* w0 = (const float*)d_in[7];
  const float* gamma = (const float*)d_in[8];
  const float* beta = (const float*)d_in[9];
  float* out = (float*)d_out;

  const size_t NE = (size_t)BB * SS * DM;
  float* Q = (float*)d_ws;
  float* K = Q + NE;
  float* V = K + NE;
  float* AO = V + NE;
  float* P = Q;  // projection output reuses Q's buffer (Q dead after attn)

  const int M = BB * SS;  // 8192
  dim3 gg(DM / 64, M / 64);
  gemm_k<<<gg, 256, 0, stream>>>(xq, wq, Q, M, DM, DM);
  gemm_k<<<gg, 256, 0, stream>>>(xk, wk, K, M, DM, DM);
  gemm_k<<<gg, 256, 0, stream>>>(xv, wv, V, M, DM, DM);
  attn_tile_k<<<dim3(SS / 64, NH, BB), 256, 0, stream>>>(Q, K, V, mask, AO);
  gemm_k<<<gg, 256, 0, stream>>>(AO, w0, P, M, DM, DM);
  ln_k<<<M, 256, 0, stream>>>(P, xq, gamma, beta, out);
}

// Round 4
// 777.447 us; speedup vs baseline: 14.6789x; 6.8608x over previous
//
#include <hip/hip_runtime.h>
#include <hip/hip_bf16.h>

#define DM 1024
#define NH 16
#define DK 64
#define BB 4
#define SS 2048
#define EPSV 1e-6f

typedef __attribute__((ext_vector_type(8))) short short8;
typedef __attribute__((ext_vector_type(4))) float f32x4;

__device__ inline unsigned short f2bf(float x) {
  unsigned int u = __builtin_bit_cast(unsigned int, x);
  u += 0x7FFF + ((u >> 16) & 1);  // round-to-nearest-even
  return (unsigned short)(u >> 16);
}
__device__ inline ushort4 f2bf4(float4 v) {
  ushort4 r;
  r.x = f2bf(v.x); r.y = f2bf(v.y); r.z = f2bf(v.z); r.w = f2bf(v.w);
  return r;
}

// Pack int32 mask -> 1 bit per element. bm[w] covers mask[w*64 .. w*64+63].
__global__ __launch_bounds__(256) void maskbits_k(const int* __restrict__ mask,
                                                  unsigned long long* __restrict__ bm) {
  const int total = BB * SS * (SS / 64);
  int lane = threadIdx.x & 63;
  int wid = (blockIdx.x * 256 + threadIdx.x) >> 6;
  int nw = (gridDim.x * 256) >> 6;
  for (int w = wid; w < total; w += nw) {
    int v = mask[(size_t)w * 64 + lane];
    unsigned long long bal = __ballot(v != 0);
    if (lane == 0) bm[w] = bal;
  }
}

// C[M,N] = A[M,K] @ W[K,N]; f32 in/out, bf16 MFMA 16x16x32 inside.
// 128x128 tile, BK=32, 256 threads = 4 waves (2x2 grid of 64x64 per wave).
__global__ __launch_bounds__(256) void gemm_mfma_k(const float* __restrict__ A,
                                                   const float* __restrict__ W,
                                                   float* __restrict__ C,
                                                   int M, int N, int K) {
  __shared__ __align__(16) unsigned short As[128 * 40];  // [m][k] stride 40
  __shared__ __align__(16) unsigned short WB[32 * 128];  // fragment-ordered
  int bm = blockIdx.y * 128, bn = blockIdx.x * 128;
  int tid = threadIdx.x;
  int lane = tid & 63, w = tid >> 6;
  int quad = lane >> 4, c = lane & 15;
  int wx = w & 1, wy = w >> 1;

  f32x4 acc[4][4];
#pragma unroll
  for (int mt = 0; mt < 4; ++mt)
#pragma unroll
    for (int nt = 0; nt < 4; ++nt)
#pragma unroll
      for (int r = 0; r < 4; ++r) acc[mt][nt][r] = 0.f;

  int ak4 = (tid & 7) * 4, am = tid >> 3;        // A staging coords
  int wn = tid & 127, wkb = (tid >> 7) * 4;      // W staging coords
  int wnt = wn >> 4, wc = wn & 15;

  for (int k0 = 0; k0 < K; k0 += 32) {
    // Stage A tile 128x32 (rows, f32->bf16)
#pragma unroll
    for (int p = 0; p < 4; ++p) {
      int m = am + p * 32;
      float4 av = *(const float4*)&A[(size_t)(bm + m) * K + k0 + ak4];
      *(ushort4*)&As[m * 40 + ak4] = f2bf4(av);
    }
    // Stage W tile 32x128 fragment-ordered: WB[((nt*4+quad)*16+c)*8+j] = W[k][n]
#pragma unroll
    for (int s = 0; s < 4; ++s) {
      int k = wkb + s * 8;
      int q = (k >> 3) & 3, j = k & 7;  // j in {0,4}; rows k..k+3 share (q, j-base)
      ushort4 pk;
      pk.x = f2bf(W[(size_t)(k0 + k) * N + bn + wn]);
      pk.y = f2bf(W[(size_t)(k0 + k + 1) * N + bn + wn]);
      pk.z = f2bf(W[(size_t)(k0 + k + 2) * N + bn + wn]);
      pk.w = f2bf(W[(size_t)(k0 + k + 3) * N + bn + wn]);
      *(ushort4*)&WB[((wnt * 4 + q) * 16 + wc) * 8 + j] = pk;
    }
    __syncthreads();
    short8 af[4], bfr[4];
#pragma unroll
    for (int mt = 0; mt < 4; ++mt)
      af[mt] = *(const short8*)&As[(wy * 64 + mt * 16 + c) * 40 + quad * 8];
#pragma unroll
    for (int nt = 0; nt < 4; ++nt)
      bfr[nt] = *(const short8*)&WB[(((wx * 4 + nt) * 4 + quad) * 16 + c) * 8];
#pragma unroll
    for (int mt = 0; mt < 4; ++mt)
#pragma unroll
      for (int nt = 0; nt < 4; ++nt)
        acc[mt][nt] = __builtin_amdgcn_mfma_f32_16x16x32_bf16(af[mt], bfr[nt], acc[mt][nt], 0, 0, 0);
    __syncthreads();
  }
#pragma unroll
  for (int mt = 0; mt < 4; ++mt)
#pragma unroll
    for (int nt = 0; nt < 4; ++nt)
#pragma unroll
      for (int r = 0; r < 4; ++r)
        C[(size_t)(bm + wy * 64 + mt * 16 + quad * 4 + r) * N + bn + wx * 64 + nt * 16 + c] =
            acc[mt][nt][r];
}

// MFMA flash attention. Block per (b, h, 64-q tile); 4 waves, wave = 16-q strip.
// Q,K,V,O: [B,S,H,D] f32. mask==0 -> score = 1e-6 (exactly as reference).
__global__ __launch_bounds__(256) void attn_mfma_k(const float* __restrict__ Q,
                                                   const float* __restrict__ Kg,
                                                   const float* __restrict__ V,
                                                   const unsigned long long* __restrict__ bm,
                                                   float* __restrict__ O) {
  __shared__ __align__(16) unsigned short Ks[64 * 72];  // [k][d] stride 72
  __shared__ __align__(16) unsigned short VB[64 * 64];  // fragment-ordered
  __shared__ __align__(16) unsigned short Ps[64 * 72];  // [q][k] stride 72
  int b = blockIdx.z, h = blockIdx.y, q0 = blockIdx.x * 64;
  int tid = threadIdx.x, lane = tid & 63, w = tid >> 6;
  int quad = lane >> 4, c = lane & 15;

  // Preload Q A-fragments (row = w*16+c, k-dim = d)
  short8 qf[2];
  {
    int q = q0 + w * 16 + c;
    const float* qp = Q + (((size_t)b * SS + q) * NH + h) * DK;
#pragma unroll
    for (int dkt = 0; dkt < 2; ++dkt) {
      float4 a = *(const float4*)&qp[dkt * 32 + quad * 8];
      float4 bq = *(const float4*)&qp[dkt * 32 + quad * 8 + 4];
      union { short8 v; ushort4 u[2]; } t;
      t.u[0] = f2bf4(a);
      t.u[1] = f2bf4(bq);
      qf[dkt] = t.v;
    }
  }

  float mrow[4] = {-1e30f, -1e30f, -1e30f, -1e30f};
  float lrow[4] = {0.f, 0.f, 0.f, 0.f};
  f32x4 accO[4];
#pragma unroll
  for (int dt = 0; dt < 4; ++dt)
#pragma unroll
    for (int r = 0; r < 4; ++r) accO[dt][r] = 0.f;

  int kd4 = (tid & 15) * 4, kkb = tid >> 4;   // K staging
  int vd = tid & 63, vkb = (tid >> 6) * 4;    // V staging
  int vdt = vd >> 4, vc = vd & 15;

  for (int kt = 0; kt < SS / 64; ++kt) {
    int k0 = kt * 64;
    // Stage K rows (natural [k][d])
#pragma unroll
    for (int kk = 0; kk < 4; ++kk) {
      int kr = kkb + kk * 16;
      float4 kv = *(const float4*)&Kg[(((size_t)b * SS + k0 + kr) * NH + h) * DK + kd4];
      *(ushort4*)&Ks[kr * 72 + kd4] = f2bf4(kv);
    }
    // Stage V fragment-ordered: VB[(((kt2*4+dt)*4+quad)*16+c)*8+j] = V[k][d]
#pragma unroll
    for (int s = 0; s < 4; ++s) {
      int kr = vkb + s * 16;
      int vq = (kr >> 3) & 3, vj = kr & 7, vkt = kr >> 5;
      const float* vp = &V[(((size_t)b * SS + k0 + kr) * NH + h) * DK + vd];
      ushort4 pk;
      pk.x = f2bf(vp[0]);
      pk.y = f2bf(vp[(size_t)NH * DK]);
      pk.z = f2bf(vp[(size_t)2 * NH * DK]);
      pk.w = f2bf(vp[(size_t)3 * NH * DK]);
      *(ushort4*)&VB[(((vkt * 4 + vdt) * 4 + vq) * 16 + vc) * 8 + vj] = pk;
    }
    __syncthreads();

    // S = Q K^T  (16q x 64k per wave)
    f32x4 sacc[4];
#pragma unroll
    for (int nt = 0; nt < 4; ++nt)
#pragma unroll
      for (int r = 0; r < 4; ++r) sacc[nt][r] = 0.f;
#pragma unroll
    for (int dkt = 0; dkt < 2; ++dkt)
#pragma unroll
      for (int nt = 0; nt < 4; ++nt) {
        short8 kfrag = *(const short8*)&Ks[(nt * 16 + c) * 72 + dkt * 32 + quad * 8];
        sacc[nt] = __builtin_amdgcn_mfma_f32_16x16x32_bf16(qf[dkt], kfrag, sacc[nt], 0, 0, 0);
      }

    // mask + online softmax in fragment space (rows quad*4+r, cols nt*16+c)
    float alpha[4];
#pragma unroll
    for (int r = 0; r < 4; ++r) {
      int q = q0 + w * 16 + quad * 4 + r;
      unsigned long long mw = bm[((size_t)b * SS + q) * (SS / 64) + kt];
      float sv[4];
#pragma unroll
      for (int nt = 0; nt < 4; ++nt) {
        int bit = (int)((mw >> (nt * 16 + c)) & 1ull);
        sv[nt] = bit ? sacc[nt][r] * 0.125f : EPSV;
      }
      float tm = fmaxf(fmaxf(sv[0], sv[1]), fmaxf(sv[2], sv[3]));
      tm = fmaxf(tm, __shfl_xor(tm, 1));
      tm = fmaxf(tm, __shfl_xor(tm, 2));
      tm = fmaxf(tm, __shfl_xor(tm, 4));
      tm = fmaxf(tm, __shfl_xor(tm, 8));
      float mnew = fmaxf(mrow[r], tm);
      float al = __expf(mrow[r] - mnew);
      float p0 = __expf(sv[0] - mnew);
      float p1 = __expf(sv[1] - mnew);
      float p2 = __expf(sv[2] - mnew);
      float p3 = __expf(sv[3] - mnew);
      float rs = (p0 + p1) + (p2 + p3);
      rs += __shfl_xor(rs, 1);
      rs += __shfl_xor(rs, 2);
      rs += __shfl_xor(rs, 4);
      rs += __shfl_xor(rs, 8);
      lrow[r] = lrow[r] * al + rs;
      mrow[r] = mnew;
      alpha[r] = al;
      int prow = (w * 16 + quad * 4 + r) * 72;
      Ps[prow + c] = f2bf(p0);
      Ps[prow + 16 + c] = f2bf(p1);
      Ps[prow + 32 + c] = f2bf(p2);
      Ps[prow + 48 + c] = f2bf(p3);
    }
    // Ps is wave-private (each wave reads only its own 16-row strip): no barrier.

#pragma unroll
    for (int dt = 0; dt < 4; ++dt) {
      f32x4 a = accO[dt];
      a[0] *= alpha[0]; a[1] *= alpha[1]; a[2] *= alpha[2]; a[3] *= alpha[3];
      accO[dt] = a;
    }
#pragma unroll
    for (int pkt = 0; pkt < 2; ++pkt) {
      short8 pf = *(const short8*)&Ps[(w * 16 + c) * 72 + pkt * 32 + quad * 8];
#pragma unroll
      for (int dt = 0; dt < 4; ++dt) {
        short8 vf = *(const short8*)&VB[(((pkt * 4 + dt) * 4 + quad) * 16 + c) * 8];
        accO[dt] = __builtin_amdgcn_mfma_f32_16x16x32_bf16(pf, vf, accO[dt], 0, 0, 0);
      }
    }
    __syncthreads();  // all waves done with Ks/VB before next stage
  }

  float inv[4];
#pragma unroll
  for (int r = 0; r < 4; ++r) inv[r] = 1.f / lrow[r];
#pragma unroll
  for (int dt = 0; dt < 4; ++dt)
#pragma unroll
    for (int r = 0; r < 4; ++r) {
      int q = q0 + w * 16 + quad * 4 + r;
      O[(((size_t)b * SS + q) * NH + h) * DK + dt * 16 + c] = accO[dt][r] * inv[r];
    }
}

// Residual + LayerNorm (ddof=1 std, eps added to std), f32 out.
__global__ __launch_bounds__(256) void ln_k(const float* __restrict__ P,
                                            const float* __restrict__ X,
                                            const float* __restrict__ gamma,
                                            const float* __restrict__ beta,
                                            float* __restrict__ out) {
  int row = blockIdx.x, tid = threadIdx.x;
  __shared__ float buf[DM];
  __shared__ float red[256];
  float local = 0.f;
  for (int i = tid; i < DM; i += 256) {
    float v = P[(size_t)row * DM + i] + X[(size_t)row * DM + i];
    buf[i] = v;
    local += v;
  }
  red[tid] = local;
  __syncthreads();
  for (int st = 128; st > 0; st >>= 1) {
    if (tid < st) red[tid] += red[tid + st];
    __syncthreads();
  }
  float mean = red[0] * (1.f / DM);
  __syncthreads();
  float l2 = 0.f;
  for (int i = tid; i < DM; i += 256) {
    float dd = buf[i] - mean;
    l2 += dd * dd;
  }
  red[tid] = l2;
  __syncthreads();
  for (int st = 128; st > 0; st >>= 1) {
    if (tid < st) red[tid] += red[tid + st];
    __syncthreads();
  }
  float stdv = sqrtf(red[0] / (DM - 1));
  float inv = 1.f / (stdv + EPSV);
  for (int i = tid; i < DM; i += 256) {
    float y = gamma[i] * (buf[i] - mean) * inv + beta[i];
    out[(size_t)row * DM + i] = y;
  }
}

extern "C" void kernel_launch(void* const* d_in, const int* in_sizes, int n_in,
                              void* d_out, int out_size, void* d_ws, size_t ws_size,
                              hipStream_t stream) {
  const float* xq = (const float*)d_in[0];
  const float* xk = (const float*)d_in[1];
  const float* xv = (const float*)d_in[2];
  const int* mask = (const int*)d_in[3];
  const float* wq = (const float*)d_in[4];
  const float* wk = (const float*)d_in[5];
  const float* wv = (const float*)d_in[6];
  const float* w0 = (const float*)d_in[7];
  const float* gamma = (const float*)d_in[8];
  const float* beta = (const float*)d_in[9];
  float* out = (float*)d_out;

  const size_t NE = (size_t)BB * SS * DM;
  float* Q = (float*)d_ws;
  float* K = Q + NE;
  float* V = K + NE;
  float* AO = V + NE;
  float* P = Q;  // w0-GEMM output reuses Q (dead after attention)
  // mask bitmask parked in d_out (2 MB); LN overwrites d_out at the very end.
  unsigned long long* bm = (unsigned long long*)d_out;

  const int M = BB * SS;  // 8192
  maskbits_k<<<256, 256, 0, stream>>>(mask, bm);
  dim3 gg(DM / 128, M / 128);
  gemm_mfma_k<<<gg, 256, 0, stream>>>(xq, wq, Q, M, DM, DM);
  gemm_mfma_k<<<gg, 256, 0, stream>>>(xk, wk, K, M, DM, DM);
  gemm_mfma_k<<<gg, 256, 0, stream>>>(xv, wv, V, M, DM, DM);
  attn_mfma_k<<<dim3(SS / 64, NH, BB), 256, 0, stream>>>(Q, K, V, bm, AO);
  gemm_mfma_k<<<gg, 256, 0, stream>>>(AO, w0, P, M, DM, DM);
  ln_k<<<M, 256, 0, stream>>>(P, xq, gamma, beta, out);
}

// Round 5
// 739.856 us; speedup vs baseline: 15.4247x; 1.0508x over previous
//
#include <hip/hip_runtime.h>
#include <hip/hip_bf16.h>

#define DM 1024
#define NH 16
#define DK 64
#define BB 4
#define SS 2048
#define EPSV 1e-6f
#define NE ((size_t)BB * SS * DM)  // 8388608
#define MM ((size_t)DM * DM)       // 1048576

typedef __attribute__((ext_vector_type(8))) short short8;
typedef __attribute__((ext_vector_type(4))) float f32x4;

__device__ inline unsigned short f2bf(float x) {
  unsigned int u = __builtin_bit_cast(unsigned int, x);
  u += 0x7FFF + ((u >> 16) & 1);  // RNE
  return (unsigned short)(u >> 16);
}
__device__ inline ushort4 f2bf4(float4 v) {
  ushort4 r;
  r.x = f2bf(v.x); r.y = f2bf(v.y); r.z = f2bf(v.z); r.w = f2bf(v.w);
  return r;
}

// ---- Pre-pass: x tensors f32 -> bf16 (elementwise, float4) ----
__global__ __launch_bounds__(256) void cvt_x_k(const float* __restrict__ xq,
                                               const float* __restrict__ xk,
                                               const float* __restrict__ xv,
                                               unsigned short* __restrict__ oq,
                                               unsigned short* __restrict__ ok,
                                               unsigned short* __restrict__ ov) {
  const size_t NF4 = NE / 4;
  size_t g = (size_t)blockIdx.x * 256 + threadIdx.x;  // grid covers 3*NF4
  int t = (int)(g / NF4);
  size_t i = g - (size_t)t * NF4;
  const float* s = (t == 0) ? xq : (t == 1) ? xk : xv;
  unsigned short* d = (t == 0) ? oq : (t == 1) ? ok : ov;
  float4 v = ((const float4*)s)[i];
  ((ushort4*)d)[i] = f2bf4(v);
}

// ---- Pre-pass: W[k][n] f32 -> WT[n][k] bf16 (LDS transpose) ----
__global__ __launch_bounds__(256) void cvt_wT_k(const float* __restrict__ w0,
                                                const float* __restrict__ w1,
                                                const float* __restrict__ w2,
                                                const float* __restrict__ w3,
                                                unsigned short* __restrict__ o0,
                                                unsigned short* __restrict__ o1,
                                                unsigned short* __restrict__ o2,
                                                unsigned short* __restrict__ o3) {
  __shared__ float t[32][33];
  int z = blockIdx.z;
  const float* w = (z == 0) ? w0 : (z == 1) ? w1 : (z == 2) ? w2 : w3;
  unsigned short* o = (z == 0) ? o0 : (z == 1) ? o1 : (z == 2) ? o2 : o3;
  int n0 = blockIdx.x * 32, k0 = blockIdx.y * 32;
  int tx = threadIdx.x & 31, ty = threadIdx.x >> 5;
#pragma unroll
  for (int s = 0; s < 4; ++s) t[ty + s * 8][tx] = w[(size_t)(k0 + ty + s * 8) * DM + n0 + tx];
  __syncthreads();
#pragma unroll
  for (int s = 0; s < 4; ++s)
    o[(size_t)(n0 + ty + s * 8) * DM + k0 + tx] = f2bf(t[tx][ty + s * 8]);
}

// ---- Pre-pass: pack int32 mask -> 1 bit ----
__global__ __launch_bounds__(256) void maskbits_k(const int* __restrict__ mask,
                                                  unsigned long long* __restrict__ bm) {
  const int total = BB * SS * (SS / 64);
  int lane = threadIdx.x & 63;
  int wid = (blockIdx.x * 256 + threadIdx.x) >> 6;
  int nw = (gridDim.x * 256) >> 6;
  for (int w = wid; w < total; w += nw) {
    int v = mask[(size_t)w * 64 + lane];
    unsigned long long bal = __ballot(v != 0);
    if (lane == 0) bm[w] = bal;
  }
}

// ---- Direct-fragment MFMA GEMM: C[M,N] = A[M,K](bf16) @ WT[N,K](bf16)^T ----
// 128x128 block, 4 waves (2x2 of 64x64), fragments loaded straight from global (L2-hot).
template <bool BF16OUT>
__global__ __launch_bounds__(256) void gemm_dir_k(const unsigned short* __restrict__ A,
                                                  const unsigned short* __restrict__ WT,
                                                  void* __restrict__ Cv,
                                                  int M, int N, int K) {
  int bm = blockIdx.y * 128, bn = blockIdx.x * 128;
  int tid = threadIdx.x, lane = tid & 63, w = tid >> 6;
  int quad = lane >> 4, c = lane & 15;
  int wx = w & 1, wy = w >> 1;

  f32x4 acc[4][4];
#pragma unroll
  for (int mt = 0; mt < 4; ++mt)
#pragma unroll
    for (int nt = 0; nt < 4; ++nt)
#pragma unroll
      for (int r = 0; r < 4; ++r) acc[mt][nt][r] = 0.f;

  const unsigned short* Ab = A + (size_t)(bm + wy * 64 + c) * K + quad * 8;
  const unsigned short* Wb = WT + (size_t)(bn + wx * 64 + c) * K + quad * 8;

  for (int k0 = 0; k0 < K; k0 += 32) {
    short8 af[4], bf[4];
#pragma unroll
    for (int mt = 0; mt < 4; ++mt) af[mt] = *(const short8*)(Ab + (size_t)mt * 16 * K + k0);
#pragma unroll
    for (int nt = 0; nt < 4; ++nt) bf[nt] = *(const short8*)(Wb + (size_t)nt * 16 * K + k0);
#pragma unroll
    for (int mt = 0; mt < 4; ++mt)
#pragma unroll
      for (int nt = 0; nt < 4; ++nt)
        acc[mt][nt] = __builtin_amdgcn_mfma_f32_16x16x32_bf16(af[mt], bf[nt], acc[mt][nt], 0, 0, 0);
  }
#pragma unroll
  for (int mt = 0; mt < 4; ++mt)
#pragma unroll
    for (int nt = 0; nt < 4; ++nt)
#pragma unroll
      for (int r = 0; r < 4; ++r) {
        size_t idx = (size_t)(bm + wy * 64 + mt * 16 + quad * 4 + r) * N + bn + wx * 64 + nt * 16 + c;
        if (BF16OUT)
          ((unsigned short*)Cv)[idx] = f2bf(acc[mt][nt][r]);
        else
          ((float*)Cv)[idx] = acc[mt][nt][r];
      }
}

// ---- MFMA flash attention, bf16 IO, fixed-shift softmax (C=0) ----
// Block per (b, h, 64-q tile); 4 waves = 16-q strips. mask==0 -> p=1 (== exp(eps)).
__global__ __launch_bounds__(256) void attn_mfma_k(const unsigned short* __restrict__ Q,
                                                   const unsigned short* __restrict__ Kg,
                                                   const unsigned short* __restrict__ V,
                                                   const unsigned long long* __restrict__ bm,
                                                   unsigned short* __restrict__ O) {
  __shared__ __align__(16) unsigned short Ks[64 * 72];  // [key][d] stride 72
  __shared__ __align__(16) unsigned short VB[64 * 64];  // fragment-ordered
  __shared__ __align__(16) unsigned short Ps[64 * 72];  // [q][key] stride 72
  int b = blockIdx.z, h = blockIdx.y, q0 = blockIdx.x * 64;
  int tid = threadIdx.x, lane = tid & 63, w = tid >> 6;
  int quad = lane >> 4, c = lane & 15;

  // Q A-fragments straight from global bf16
  short8 qf[2];
  {
    const unsigned short* qp = Q + ((size_t)b * SS + q0 + w * 16 + c) * DM + h * DK + quad * 8;
    qf[0] = *(const short8*)qp;
    qf[1] = *(const short8*)(qp + 32);
  }

  float lpart[4] = {0.f, 0.f, 0.f, 0.f};
  f32x4 accO[4];
#pragma unroll
  for (int dt = 0; dt < 4; ++dt)
#pragma unroll
    for (int r = 0; r < 4; ++r) accO[dt][r] = 0.f;

  int krow = tid >> 3, kd = (tid & 7) * 8;   // K staging: 8 lanes per 64-bf16 row
  int vd = tid & 63, vkb = (tid >> 6) * 8;   // V staging
  int vdt = vd >> 4, vc = vd & 15;

  for (int kt = 0; kt < SS / 64; ++kt) {
    int k0 = kt * 64;
#pragma unroll
    for (int pass = 0; pass < 2; ++pass) {
      int kr = krow + pass * 32;
      short8 kv = *(const short8*)&Kg[((size_t)b * SS + k0 + kr) * DM + h * DK + kd];
      *(short8*)&Ks[kr * 72 + kd] = kv;
    }
#pragma unroll
    for (int s = 0; s < 2; ++s) {
      int kb = vkb + s * 32;
      const unsigned short* vp = &V[((size_t)b * SS + k0 + kb) * DM + h * DK + vd];
      union { short8 v; unsigned short u[8]; } pk;
#pragma unroll
      for (int j = 0; j < 8; ++j) pk.u[j] = vp[(size_t)j * DM];
      *(short8*)&VB[(((kb >> 5) * 4 + vdt) * 4 + ((kb >> 3) & 3)) * 128 + vc * 8] = pk.v;
    }
    __syncthreads();

    // S = Q K^T (16q x 64k per wave)
    f32x4 sacc[4];
#pragma unroll
    for (int nt = 0; nt < 4; ++nt)
#pragma unroll
      for (int r = 0; r < 4; ++r) sacc[nt][r] = 0.f;
#pragma unroll
    for (int dkt = 0; dkt < 2; ++dkt)
#pragma unroll
      for (int nt = 0; nt < 4; ++nt) {
        short8 kfrag = *(const short8*)&Ks[(nt * 16 + c) * 72 + dkt * 32 + quad * 8];
        sacc[nt] = __builtin_amdgcn_mfma_f32_16x16x32_bf16(qf[dkt], kfrag, sacc[nt], 0, 0, 0);
      }

    // p = maskbit ? exp(s/8) : 1.0 ; no max shift (softmax is shift-invariant, s ~ O(10))
#pragma unroll
    for (int r = 0; r < 4; ++r) {
      int q = q0 + w * 16 + quad * 4 + r;
      unsigned long long mw = bm[((size_t)b * SS + q) * (SS / 64) + kt];
      int prow = (w * 16 + quad * 4 + r) * 72;
      float rs = 0.f;
#pragma unroll
      for (int nt = 0; nt < 4; ++nt) {
        float p = ((mw >> (nt * 16 + c)) & 1ull) ? __expf(sacc[nt][r] * 0.125f) : 1.0f;
        rs += p;
        Ps[prow + nt * 16 + c] = f2bf(p);
      }
      lpart[r] += rs;
    }
    // Ps strip is wave-private: no barrier before PV.

#pragma unroll
    for (int pkt = 0; pkt < 2; ++pkt) {
      short8 pf = *(const short8*)&Ps[(w * 16 + c) * 72 + pkt * 32 + quad * 8];
#pragma unroll
      for (int dt = 0; dt < 4; ++dt) {
        short8 vf = *(const short8*)&VB[((pkt * 4 + dt) * 4 + quad) * 128 + c * 8];
        accO[dt] = __builtin_amdgcn_mfma_f32_16x16x32_bf16(pf, vf, accO[dt], 0, 0, 0);
      }
    }
    __syncthreads();
  }

  // one reduction at the very end: row-sum over the 16 lanes of the quad
  float inv[4];
#pragma unroll
  for (int r = 0; r < 4; ++r) {
    float l = lpart[r];
    l += __shfl_xor(l, 1);
    l += __shfl_xor(l, 2);
    l += __shfl_xor(l, 4);
    l += __shfl_xor(l, 8);
    inv[r] = 1.f / l;
  }
#pragma unroll
  for (int dt = 0; dt < 4; ++dt)
#pragma unroll
    for (int r = 0; r < 4; ++r) {
      int q = q0 + w * 16 + quad * 4 + r;
      O[((size_t)b * SS + q) * DM + h * DK + dt * 16 + c] = f2bf(accO[dt][r] * inv[r]);
    }
}

// ---- Residual + LayerNorm (ddof=1, eps on std), vectorized ----
__global__ __launch_bounds__(256) void ln_k(const float* __restrict__ P,
                                            const float* __restrict__ X,
                                            const float* __restrict__ gamma,
                                            const float* __restrict__ beta,
                                            float* __restrict__ out) {
  __shared__ float sm[4];
  int row = blockIdx.x, tid = threadIdx.x, w = tid >> 6;
  float4 p = ((const float4*)(P + (size_t)row * DM))[tid];
  float4 x = ((const float4*)(X + (size_t)row * DM))[tid];
  float4 v = make_float4(p.x + x.x, p.y + x.y, p.z + x.z, p.w + x.w);
  float s = (v.x + v.y) + (v.z + v.w);
#pragma unroll
  for (int off = 1; off < 64; off <<= 1) s += __shfl_xor(s, off);
  if ((tid & 63) == 0) sm[w] = s;
  __syncthreads();
  float mean = (sm[0] + sm[1] + sm[2] + sm[3]) * (1.f / DM);
  __syncthreads();
  float dx = v.x - mean, dy = v.y - mean, dz = v.z - mean, dw = v.w - mean;
  float s2 = (dx * dx + dy * dy) + (dz * dz + dw * dw);
#pragma unroll
  for (int off = 1; off < 64; off <<= 1) s2 += __shfl_xor(s2, off);
  if ((tid & 63) == 0) sm[w] = s2;
  __syncthreads();
  float var = (sm[0] + sm[1] + sm[2] + sm[3]) * (1.f / (DM - 1));
  float inv = 1.f / (sqrtf(var) + EPSV);
  float4 g = ((const float4*)gamma)[tid];
  float4 be = ((const float4*)beta)[tid];
  float4 y = make_float4(g.x * dx * inv + be.x, g.y * dy * inv + be.y,
                         g.z * dz * inv + be.z, g.w * dw * inv + be.w);
  ((float4*)(out + (size_t)row * DM))[tid] = y;
}

extern "C" void kernel_launch(void* const* d_in, const int* in_sizes, int n_in,
                              void* d_out, int out_size, void* d_ws, size_t ws_size,
                              hipStream_t stream) {
  const float* xq = (const float*)d_in[0];
  const float* xk = (const float*)d_in[1];
  const float* xv = (const float*)d_in[2];
  const int* mask = (const int*)d_in[3];
  const float* wq = (const float*)d_in[4];
  const float* wk = (const float*)d_in[5];
  const float* wv = (const float*)d_in[6];
  const float* w0 = (const float*)d_in[7];
  const float* gamma = (const float*)d_in[8];
  const float* beta = (const float*)d_in[9];
  float* out = (float*)d_out;

  // ws layout (bf16 elements unless noted):
  // [xqb NE][xkb NE][xvb NE][wTq MM][wTk MM][wTv MM][wT0 MM][Qb NE][Kb NE][Vb NE][AOb NE]
  // P (f32, NE) overlays Qb+Kb (dead after attention). Total ~125.6 MB.
  unsigned short* xqb = (unsigned short*)d_ws;
  unsigned short* xkb = xqb + NE;
  unsigned short* xvb = xkb + NE;
  unsigned short* wTq = xvb + NE;
  unsigned short* wTk = wTq + MM;
  unsigned short* wTv = wTk + MM;
  unsigned short* wT0 = wTv + MM;
  unsigned short* Qb = wT0 + MM;
  unsigned short* Kb = Qb + NE;
  unsigned short* Vb = Kb + NE;
  unsigned short* AOb = Vb + NE;
  float* P = (float*)Qb;
  unsigned long long* bm = (unsigned long long*)d_out;  // 2 MB, overwritten by ln_k at the end

  const int M = BB * SS;  // 8192
  cvt_x_k<<<(unsigned)(3 * (NE / 4) / 256), 256, 0, stream>>>(xq, xk, xv, xqb, xkb, xvb);
  cvt_wT_k<<<dim3(32, 32, 4), 256, 0, stream>>>(wq, wk, wv, w0, wTq, wTk, wTv, wT0);
  maskbits_k<<<256, 256, 0, stream>>>(mask, bm);
  dim3 gg(DM / 128, M / 128);
  gemm_dir_k<true><<<gg, 256, 0, stream>>>(xqb, wTq, Qb, M, DM, DM);
  gemm_dir_k<true><<<gg, 256, 0, stream>>>(xkb, wTk, Kb, M, DM, DM);
  gemm_dir_k<true><<<gg, 256, 0, stream>>>(xvb, wTv, Vb, M, DM, DM);
  attn_mfma_k<<<dim3(SS / 64, NH, BB), 256, 0, stream>>>(Qb, Kb, Vb, bm, AOb);
  gemm_dir_k<false><<<gg, 256, 0, stream>>>(AOb, wT0, P, M, DM, DM);
  ln_k<<<M, 256, 0, stream>>>(P, xq, gamma, beta, out);
}

// Round 6
// 602.274 us; speedup vs baseline: 18.9483x; 1.2284x over previous
//
#include <hip/hip_runtime.h>
#include <hip/hip_bf16.h>

#define DM 1024
#define NH 16
#define DK 64
#define BB 4
#define SS 2048
#define EPSV 1e-6f
#define NE ((size_t)BB * SS * DM)  // 8388608
#define MM ((size_t)DM * DM)       // 1048576

typedef __attribute__((ext_vector_type(8))) short short8;
typedef __attribute__((ext_vector_type(4))) float f32x4;

__device__ inline unsigned short f2bf(float x) {
  unsigned int u = __builtin_bit_cast(unsigned int, x);
  u += 0x7FFF + ((u >> 16) & 1);  // RNE
  return (unsigned short)(u >> 16);
}
__device__ inline ushort4 f2bf4(float4 v) {
  ushort4 r;
  r.x = f2bf(v.x); r.y = f2bf(v.y); r.z = f2bf(v.z); r.w = f2bf(v.w);
  return r;
}

// async global->LDS, 16B per lane; LDS dest = wave-uniform base + lane*16
__device__ inline void gl_lds16(const unsigned short* g, unsigned short* l) {
  __builtin_amdgcn_global_load_lds((const __attribute__((address_space(1))) void*)g,
                                   (__attribute__((address_space(3))) void*)l, 16, 0, 0);
}

// ---- Pre-pass: x tensors f32 -> bf16 (elementwise, float4) ----
__global__ __launch_bounds__(256) void cvt_x_k(const float* __restrict__ xq,
                                               const float* __restrict__ xk,
                                               const float* __restrict__ xv,
                                               unsigned short* __restrict__ oq,
                                               unsigned short* __restrict__ ok,
                                               unsigned short* __restrict__ ov) {
  const size_t NF4 = NE / 4;
  size_t g = (size_t)blockIdx.x * 256 + threadIdx.x;
  int t = (int)(g / NF4);
  size_t i = g - (size_t)t * NF4;
  const float* s = (t == 0) ? xq : (t == 1) ? xk : xv;
  unsigned short* d = (t == 0) ? oq : (t == 1) ? ok : ov;
  float4 v = ((const float4*)s)[i];
  ((ushort4*)d)[i] = f2bf4(v);
}

// ---- Pre-pass: W[k][n] f32 -> WT[n][k] bf16 (LDS transpose) ----
__global__ __launch_bounds__(256) void cvt_wT_k(const float* __restrict__ w0,
                                                const float* __restrict__ w1,
                                                const float* __restrict__ w2,
                                                const float* __restrict__ w3,
                                                unsigned short* __restrict__ o0,
                                                unsigned short* __restrict__ o1,
                                                unsigned short* __restrict__ o2,
                                                unsigned short* __restrict__ o3) {
  __shared__ float t[32][33];
  int z = blockIdx.z;
  const float* w = (z == 0) ? w0 : (z == 1) ? w1 : (z == 2) ? w2 : w3;
  unsigned short* o = (z == 0) ? o0 : (z == 1) ? o1 : (z == 2) ? o2 : o3;
  int n0 = blockIdx.x * 32, k0 = blockIdx.y * 32;
  int tx = threadIdx.x & 31, ty = threadIdx.x >> 5;
#pragma unroll
  for (int s = 0; s < 4; ++s) t[ty + s * 8][tx] = w[(size_t)(k0 + ty + s * 8) * DM + n0 + tx];
  __syncthreads();
#pragma unroll
  for (int s = 0; s < 4; ++s)
    o[(size_t)(n0 + ty + s * 8) * DM + k0 + tx] = f2bf(t[tx][ty + s * 8]);
}

// ---- Pre-pass: pack int32 mask -> 1 bit ----
__global__ __launch_bounds__(256) void maskbits_k(const int* __restrict__ mask,
                                                  unsigned long long* __restrict__ bm) {
  const int total = BB * SS * (SS / 64);
  int lane = threadIdx.x & 63;
  int wid = (blockIdx.x * 256 + threadIdx.x) >> 6;
  int nw = (gridDim.x * 256) >> 6;
  for (int w = wid; w < total; w += nw) {
    int v = mask[(size_t)w * 64 + lane];
    unsigned long long bal = __ballot(v != 0);
    if (lane == 0) bm[w] = bal;
  }
}

// ---- m97-style MFMA GEMM: C = A[M,K] @ WT[N,K]^T, bf16 in, 128x128 tile, BK=32.
// global_load_lds width-16 staging into unpadded row-major LDS; z-batched.
template <bool BF16OUT>
__global__ __launch_bounds__(256) void gemm_lds_k(const unsigned short* __restrict__ Abase,
                                                  const unsigned short* __restrict__ WTbase,
                                                  void* __restrict__ Cv, int M, int N, int K,
                                                  size_t zA, size_t zW, size_t zC) {
  __shared__ __align__(16) unsigned short As[128 * 32];
  __shared__ __align__(16) unsigned short Bs[128 * 32];
  const unsigned short* A = Abase + (size_t)blockIdx.z * zA;
  const unsigned short* WT = WTbase + (size_t)blockIdx.z * zW;
  int bm = blockIdx.y * 128, bn = blockIdx.x * 128;
  int tid = threadIdx.x, lane = tid & 63, w = tid >> 6;
  int quad = lane >> 4, c = lane & 15, wx = w & 1, wy = w >> 1;

  f32x4 acc[4][4];
#pragma unroll
  for (int mt = 0; mt < 4; ++mt)
#pragma unroll
    for (int nt = 0; nt < 4; ++nt)
#pragma unroll
      for (int r = 0; r < 4; ++r) acc[mt][nt][r] = 0.f;

  // staging: wave w owns rows [32w, 32w+32); lane i -> row 32w + i/4, k-chunk (i%4)*8
  int srow = lane >> 2, scol = (lane & 3) * 8;
  const unsigned short* Ag = A + (size_t)(bm + w * 32 + srow) * K + scol;
  const unsigned short* Bg = WT + (size_t)(bn + w * 32 + srow) * K + scol;
  unsigned short* Al = &As[w * 32 * 32];
  unsigned short* Bl = &Bs[w * 32 * 32];

  for (int k0 = 0; k0 < K; k0 += 32) {
    gl_lds16(Ag + k0, Al);
    gl_lds16(Ag + (size_t)16 * K + k0, Al + 16 * 32);
    gl_lds16(Bg + k0, Bl);
    gl_lds16(Bg + (size_t)16 * K + k0, Bl + 16 * 32);
    __syncthreads();  // drains vmcnt -> LDS valid
    short8 af[4], bf[4];
#pragma unroll
    for (int mt = 0; mt < 4; ++mt) af[mt] = *(const short8*)&As[(wy * 64 + mt * 16 + c) * 32 + quad * 8];
#pragma unroll
    for (int nt = 0; nt < 4; ++nt) bf[nt] = *(const short8*)&Bs[(wx * 64 + nt * 16 + c) * 32 + quad * 8];
#pragma unroll
    for (int mt = 0; mt < 4; ++mt)
#pragma unroll
      for (int nt = 0; nt < 4; ++nt)
        acc[mt][nt] = __builtin_amdgcn_mfma_f32_16x16x32_bf16(af[mt], bf[nt], acc[mt][nt], 0, 0, 0);
    __syncthreads();  // all waves done reading before next overwrite
  }
#pragma unroll
  for (int mt = 0; mt < 4; ++mt)
#pragma unroll
    for (int nt = 0; nt < 4; ++nt)
#pragma unroll
      for (int r = 0; r < 4; ++r) {
        size_t idx = (size_t)blockIdx.z * zC +
                     (size_t)(bm + wy * 64 + mt * 16 + quad * 4 + r) * N + bn + wx * 64 + nt * 16 + c;
        if (BF16OUT)
          ((unsigned short*)Cv)[idx] = f2bf(acc[mt][nt][r]);
        else
          ((float*)Cv)[idx] = acc[mt][nt][r];
      }
}

// ---- MFMA flash attention, bf16 IO, fixed-shift softmax (unchanged from R5) ----
__global__ __launch_bounds__(256) void attn_mfma_k(const unsigned short* __restrict__ Q,
                                                   const unsigned short* __restrict__ Kg,
                                                   const unsigned short* __restrict__ V,
                                                   const unsigned long long* __restrict__ bm,
                                                   unsigned short* __restrict__ O) {
  __shared__ __align__(16) unsigned short Ks[64 * 72];
  __shared__ __align__(16) unsigned short VB[64 * 64];
  __shared__ __align__(16) unsigned short Ps[64 * 72];
  int b = blockIdx.z, h = blockIdx.y, q0 = blockIdx.x * 64;
  int tid = threadIdx.x, lane = tid & 63, w = tid >> 6;
  int quad = lane >> 4, c = lane & 15;

  short8 qf[2];
  {
    const unsigned short* qp = Q + ((size_t)b * SS + q0 + w * 16 + c) * DM + h * DK + quad * 8;
    qf[0] = *(const short8*)qp;
    qf[1] = *(const short8*)(qp + 32);
  }

  float lpart[4] = {0.f, 0.f, 0.f, 0.f};
  f32x4 accO[4];
#pragma unroll
  for (int dt = 0; dt < 4; ++dt)
#pragma unroll
    for (int r = 0; r < 4; ++r) accO[dt][r] = 0.f;

  int krow = tid >> 3, kd = (tid & 7) * 8;
  int vd = tid & 63, vkb = (tid >> 6) * 8;
  int vdt = vd >> 4, vc = vd & 15;

  for (int kt = 0; kt < SS / 64; ++kt) {
    int k0 = kt * 64;
#pragma unroll
    for (int pass = 0; pass < 2; ++pass) {
      int kr = krow + pass * 32;
      short8 kv = *(const short8*)&Kg[((size_t)b * SS + k0 + kr) * DM + h * DK + kd];
      *(short8*)&Ks[kr * 72 + kd] = kv;
    }
#pragma unroll
    for (int s = 0; s < 2; ++s) {
      int kb = vkb + s * 32;
      const unsigned short* vp = &V[((size_t)b * SS + k0 + kb) * DM + h * DK + vd];
      union { short8 v; unsigned short u[8]; } pk;
#pragma unroll
      for (int j = 0; j < 8; ++j) pk.u[j] = vp[(size_t)j * DM];
      *(short8*)&VB[(((kb >> 5) * 4 + vdt) * 4 + ((kb >> 3) & 3)) * 128 + vc * 8] = pk.v;
    }
    __syncthreads();

    f32x4 sacc[4];
#pragma unroll
    for (int nt = 0; nt < 4; ++nt)
#pragma unroll
      for (int r = 0; r < 4; ++r) sacc[nt][r] = 0.f;
#pragma unroll
    for (int dkt = 0; dkt < 2; ++dkt)
#pragma unroll
      for (int nt = 0; nt < 4; ++nt) {
        short8 kfrag = *(const short8*)&Ks[(nt * 16 + c) * 72 + dkt * 32 + quad * 8];
        sacc[nt] = __builtin_amdgcn_mfma_f32_16x16x32_bf16(qf[dkt], kfrag, sacc[nt], 0, 0, 0);
      }

#pragma unroll
    for (int r = 0; r < 4; ++r) {
      int q = q0 + w * 16 + quad * 4 + r;
      unsigned long long mw = bm[((size_t)b * SS + q) * (SS / 64) + kt];
      int prow = (w * 16 + quad * 4 + r) * 72;
      float rs = 0.f;
#pragma unroll
      for (int nt = 0; nt < 4; ++nt) {
        float p = ((mw >> (nt * 16 + c)) & 1ull) ? __expf(sacc[nt][r] * 0.125f) : 1.0f;
        rs += p;
        Ps[prow + nt * 16 + c] = f2bf(p);
      }
      lpart[r] += rs;
    }

#pragma unroll
    for (int pkt = 0; pkt < 2; ++pkt) {
      short8 pf = *(const short8*)&Ps[(w * 16 + c) * 72 + pkt * 32 + quad * 8];
#pragma unroll
      for (int dt = 0; dt < 4; ++dt) {
        short8 vf = *(const short8*)&VB[((pkt * 4 + dt) * 4 + quad) * 128 + c * 8];
        accO[dt] = __builtin_amdgcn_mfma_f32_16x16x32_bf16(pf, vf, accO[dt], 0, 0, 0);
      }
    }
    __syncthreads();
  }

  float inv[4];
#pragma unroll
  for (int r = 0; r < 4; ++r) {
    float l = lpart[r];
    l += __shfl_xor(l, 1);
    l += __shfl_xor(l, 2);
    l += __shfl_xor(l, 4);
    l += __shfl_xor(l, 8);
    inv[r] = 1.f / l;
  }
#pragma unroll
  for (int dt = 0; dt < 4; ++dt)
#pragma unroll
    for (int r = 0; r < 4; ++r) {
      int q = q0 + w * 16 + quad * 4 + r;
      O[((size_t)b * SS + q) * DM + h * DK + dt * 16 + c] = f2bf(accO[dt][r] * inv[r]);
    }
}

// ---- Residual + LayerNorm (ddof=1, eps on std), vectorized ----
__global__ __launch_bounds__(256) void ln_k(const float* __restrict__ P,
                                            const float* __restrict__ X,
                                            const float* __restrict__ gamma,
                                            const float* __restrict__ beta,
                                            float* __restrict__ out) {
  __shared__ float sm[4];
  int row = blockIdx.x, tid = threadIdx.x, w = tid >> 6;
  float4 p = ((const float4*)(P + (size_t)row * DM))[tid];
  float4 x = ((const float4*)(X + (size_t)row * DM))[tid];
  float4 v = make_float4(p.x + x.x, p.y + x.y, p.z + x.z, p.w + x.w);
  float s = (v.x + v.y) + (v.z + v.w);
#pragma unroll
  for (int off = 1; off < 64; off <<= 1) s += __shfl_xor(s, off);
  if ((tid & 63) == 0) sm[w] = s;
  __syncthreads();
  float mean = (sm[0] + sm[1] + sm[2] + sm[3]) * (1.f / DM);
  __syncthreads();
  float dx = v.x - mean, dy = v.y - mean, dz = v.z - mean, dw = v.w - mean;
  float s2 = (dx * dx + dy * dy) + (dz * dz + dw * dw);
#pragma unroll
  for (int off = 1; off < 64; off <<= 1) s2 += __shfl_xor(s2, off);
  if ((tid & 63) == 0) sm[w] = s2;
  __syncthreads();
  float var = (sm[0] + sm[1] + sm[2] + sm[3]) * (1.f / (DM - 1));
  float inv = 1.f / (sqrtf(var) + EPSV);
  float4 g = ((const float4*)gamma)[tid];
  float4 be = ((const float4*)beta)[tid];
  float4 y = make_float4(g.x * dx * inv + be.x, g.y * dy * inv + be.y,
                         g.z * dz * inv + be.z, g.w * dw * inv + be.w);
  ((float4*)(out + (size_t)row * DM))[tid] = y;
}

extern "C" void kernel_launch(void* const* d_in, const int* in_sizes, int n_in,
                              void* d_out, int out_size, void* d_ws, size_t ws_size,
                              hipStream_t stream) {
  const float* xq = (const float*)d_in[0];
  const float* xk = (const float*)d_in[1];
  const float* xv = (const float*)d_in[2];
  const int* mask = (const int*)d_in[3];
  const float* wq = (const float*)d_in[4];
  const float* wk = (const float*)d_in[5];
  const float* wv = (const float*)d_in[6];
  const float* w0 = (const float*)d_in[7];
  const float* gamma = (const float*)d_in[8];
  const float* beta = (const float*)d_in[9];
  float* out = (float*)d_out;

  // ws: [xqb NE][xkb NE][xvb NE][wTq MM][wTk MM][wTv MM][wT0 MM][Qb NE][Kb NE][Vb NE][AOb NE]
  // P (f32, NE) overlays Qb+Kb (dead after attention).
  unsigned short* xqb = (unsigned short*)d_ws;
  unsigned short* xkb = xqb + NE;
  unsigned short* xvb = xkb + NE;
  unsigned short* wTq = xvb + NE;
  unsigned short* wTk = wTq + MM;
  unsigned short* wTv = wTk + MM;
  unsigned short* wT0 = wTv + MM;
  unsigned short* Qb = wT0 + MM;
  unsigned short* Kb = Qb + NE;
  unsigned short* Vb = Kb + NE;
  unsigned short* AOb = Vb + NE;
  float* P = (float*)Qb;
  unsigned long long* bm = (unsigned long long*)d_out;  // 2 MB, dead before ln_k writes

  const int M = BB * SS;  // 8192
  cvt_x_k<<<(unsigned)(3 * (NE / 4) / 256), 256, 0, stream>>>(xq, xk, xv, xqb, xkb, xvb);
  cvt_wT_k<<<dim3(32, 32, 4), 256, 0, stream>>>(wq, wk, wv, w0, wTq, wTk, wTv, wT0);
  maskbits_k<<<256, 256, 0, stream>>>(mask, bm);
  // Q,K,V projections in ONE z-batched dispatch (1536 blocks in flight)
  gemm_lds_k<true><<<dim3(DM / 128, M / 128, 3), 256, 0, stream>>>(
      xqb, wTq, Qb, M, DM, DM, NE, MM, NE);
  attn_mfma_k<<<dim3(SS / 64, NH, BB), 256, 0, stream>>>(Qb, Kb, Vb, bm, AOb);
  gemm_lds_k<false><<<dim3(DM / 128, M / 128, 1), 256, 0, stream>>>(
      AOb, wT0, P, M, DM, DM, 0, 0, 0);
  ln_k<<<M, 256, 0, stream>>>(P, xq, gamma, beta, out);
}